// Round 2
// baseline (336.304 us; speedup 1.0000x reference)
//
#include <hip/hip_runtime.h>
#include <stdint.h>

#define NLAYERS 3
#define NQ 8
#define DIM 256          // 2^NQ
#define HALF 128         // measured output amplitudes
#define BATCH 131072

typedef float  f32x4  __attribute__((ext_vector_type(4)));
typedef __bf16 bf16x8 __attribute__((ext_vector_type(8)));

__device__ __forceinline__ unsigned short f2bf(float f){
    union { float f; uint32_t u; } v; v.f = f;
    uint32_t u = v.u;
    u += 0x7fffu + ((u >> 16) & 1u);   // round-to-nearest-even
    return (unsigned short)(u >> 16);
}

__device__ __forceinline__ float2 cmul(float2 a, float2 b){
    return make_float2(a.x*b.x - a.y*b.y, a.x*b.y + a.y*b.x);
}

// async 16B global -> LDS (lane dest = uniform base + lane*16)
__device__ __forceinline__ void gload_lds16(void* lds, const void* g){
    __builtin_amdgcn_global_load_lds(
        (const __attribute__((address_space(1))) unsigned int*)g,
        (__attribute__((address_space(3))) unsigned int*)lds,
        16, 0, 0);
}

// ---------------------------------------------------------------------------
// Kernel 1: simulate circuit on basis state e_j (block j) and emit the
// 128x256 complex matrix W as two bf16 planes (Wre, Wim), stored PRE-SWIZZLED
// (granule g of row n lands at slot g ^ (n&7)) so kernel 2 can DMA the image
// linearly into LDS and read conflict-free with ds_read_b128.
// Image: ushort[65536] = 128 KB. [0,32768): Wre, [32768,65536): Wim.
// ---------------------------------------------------------------------------
__global__ __launch_bounds__(256) void build_w_kernel(const float* __restrict__ params,
                                                      unsigned short* __restrict__ W){
    __shared__ float2 st[2][DIM];
    __shared__ float2 gm[NLAYERS*NQ][4];   // U0a,U0b,U1a,U1b per gate
    const int j = blockIdx.x;
    const int i = threadIdx.x;

    if (i < NLAYERS*NQ){
        const float* pp = params + i*3;
        float hx = 0.5f*pp[0], hy = 0.5f*pp[1], hz = 0.5f*pp[2];
        float cx = cosf(hx), sx = sinf(hx);
        float cy = cosf(hy), sy = sinf(hy);
        float cz = cosf(hz), sz = sinf(hz);
        float2 ezm = make_float2(cz, -sz), ezp = make_float2(cz, sz);
        float2 m00 = make_float2( cy*cx,  sy*sx);
        float2 m01 = make_float2(-sy*cx, -cy*sx);
        float2 m10 = make_float2( sy*cx, -cy*sx);
        float2 m11 = make_float2( cy*cx, -sy*sx);
        gm[i][0] = cmul(ezm, m00);
        gm[i][1] = cmul(ezm, m01);
        gm[i][2] = cmul(ezp, m10);
        gm[i][3] = cmul(ezp, m11);
    }

    // composed CNOT-ring permutation (params-independent, same all layers)
    int psrc = i;
    #pragma unroll
    for (int q = NQ-1; q >= 0; --q){
        int c  = 7 - q;
        int tb = 7 - ((q + 1) & 7);
        psrc = ((psrc >> c) & 1) ? (psrc ^ (1 << tb)) : psrc;
    }

    int cur = 0;
    st[0][i] = make_float2(i == j ? 1.0f : 0.0f, 0.0f);
    __syncthreads();

    for (int l = 0; l < NLAYERS; ++l){
        for (int q = 0; q < NQ; ++q){
            float2 U0a = gm[l*NQ+q][0], U0b = gm[l*NQ+q][1];
            float2 U1a = gm[l*NQ+q][2], U1b = gm[l*NQ+q][3];
            int p  = 7 - q;
            int bs = (i >> p) & 1;
            int i0 = i & ~(1 << p), i1 = i | (1 << p);
            float2 a0 = st[cur][i0], a1 = st[cur][i1];
            float2 ua = bs ? U1a : U0a;
            float2 ub = bs ? U1b : U0b;
            float2 r;
            r.x = ua.x*a0.x - ua.y*a0.y + ub.x*a1.x - ub.y*a1.y;
            r.y = ua.x*a0.y + ua.y*a0.x + ub.x*a1.y + ub.y*a1.x;
            st[cur ^ 1][i] = r;
            cur ^= 1;
            __syncthreads();
        }
        // fused CNOT ring
        float2 r = st[cur][psrc];
        st[cur ^ 1][i] = r;
        cur ^= 1;
        __syncthreads();
    }

    // column j of W: thread i<128 -> Wre[i][j], thread i>=128 -> Wim[i-128][j]
    const int m = i & 127;
    float2 a = st[cur][m];
    // swizzled offset (ushort units): row m (512 B = 32 granules of 16 B)
    const uint32_t off = (uint32_t)m*256u
                       + ((((uint32_t)j >> 3) ^ ((uint32_t)m & 7u)) << 3)
                       + ((uint32_t)j & 7u);
    if (i < 128) W[off]          = f2bf(a.x);
    else         W[32768u + off] = f2bf(a.y);
}

// ---------------------------------------------------------------------------
// Kernel 2: out[m] = sum_j |sum_k W[j][k]*(sr[m][k] + i si[m][k])|^2
// 256 blocks x 1024 threads (16 waves, 1 block/CU). B resident in 128 KB LDS
// (one barrier total). Each wave owns 32 rows (2 tiles of 16).
//
// Round-2 change: DEPTH-4 k-prefetch. A-stream loads go through a 4-slot
// static register pipeline (16 outstanding dwordx4 per wave = 256 B in
// flight, 4x round 1). The 16 global ksteps (2 tiles x 8) run as ONE flat
// fully-unrolled loop so the pipeline never drains across the tile boundary.
// All buffer indices are compile-time (rule #20: no runtime-indexed arrays).
// ---------------------------------------------------------------------------
__global__ __launch_bounds__(1024) void qform2_kernel(const float* __restrict__ sr,
                                                      const float* __restrict__ si,
                                                      const unsigned short* __restrict__ W,
                                                      float* __restrict__ out){
    __shared__ unsigned short Bs[65536];   // 128 KB: [0,32768) Wre, [32768,65536) Wim

    const int tid  = threadIdx.x;
    const int lane = tid & 63;
    const int w    = tid >> 6;        // 0..15
    const int l15  = lane & 15;
    const int quad = lane >> 4;       // 0..3
    const int xq   = l15 & 7;

    // ---- stage W image linearly: 128 chunks x 1 KB (image is pre-swizzled)
    #pragma unroll
    for (int r = 0; r < 8; ++r){
        const int c = w*8 + r;                       // 0..127
        gload_lds16(&Bs[c*512], W + (size_t)c*512 + lane*8);
    }
    __syncthreads();    // drains vmcnt -> DMA complete

    const size_t row0 = (size_t)blockIdx.x * 512 + (size_t)w * 32;
    const float* ar0 = sr + (row0 + l15) * DIM;       // tile 0 rows
    const float* ai0 = si + (row0 + l15) * DIM;
    const float* ar1 = ar0 + (size_t)16 * DIM;        // tile 1 rows
    const float* ai1 = ai0 + (size_t)16 * DIM;

    f32x4 accR[8], accI[8];
    const f32x4 z = {0.0f, 0.0f, 0.0f, 0.0f};
    #pragma unroll
    for (int jf = 0; jf < 8; ++jf){ accR[jf] = z; accI[jf] = z; }

    // 4-slot register pipeline (all indices static after full unroll)
    float4 R0[4], R1[4], Q0[4], Q1[4];

    // prologue: issue global ksteps 0..3 (tile 0)
    #pragma unroll
    for (int p = 0; p < 4; ++p){
        R0[p] = *(const float4*)(ar0 + p*32 + quad*8);
        R1[p] = *(const float4*)(ar0 + p*32 + quad*8 + 4);
        Q0[p] = *(const float4*)(ai0 + p*32 + quad*8);
        Q1[p] = *(const float4*)(ai0 + p*32 + quad*8 + 4);
    }

    #pragma unroll
    for (int kab = 0; kab < 16; ++kab){
        const int ks = kab & 7;       // kstep within tile
        const int s  = kab & 3;       // pipeline slot (compile-time)

        // ---- convert slot s: fp32 -> bf16 fragments (truncating v_perm)
        union { float4 v; uint32_t u[4]; } ha, hb;
        union { uint32_t u[4]; bf16x8 f; } pr, pi, pn;
        ha.v = R0[s]; hb.v = R1[s];
        pr.u[0] = __builtin_amdgcn_perm(ha.u[1], ha.u[0], 0x07060302);
        pr.u[1] = __builtin_amdgcn_perm(ha.u[3], ha.u[2], 0x07060302);
        pr.u[2] = __builtin_amdgcn_perm(hb.u[1], hb.u[0], 0x07060302);
        pr.u[3] = __builtin_amdgcn_perm(hb.u[3], hb.u[2], 0x07060302);
        ha.v = Q0[s]; hb.v = Q1[s];
        pi.u[0] = __builtin_amdgcn_perm(ha.u[1], ha.u[0], 0x07060302);
        pi.u[1] = __builtin_amdgcn_perm(ha.u[3], ha.u[2], 0x07060302);
        pi.u[2] = __builtin_amdgcn_perm(hb.u[1], hb.u[0], 0x07060302);
        pi.u[3] = __builtin_amdgcn_perm(hb.u[3], hb.u[2], 0x07060302);
        pn.u[0] = pi.u[0] ^ 0x80008000u;
        pn.u[1] = pi.u[1] ^ 0x80008000u;
        pn.u[2] = pi.u[2] ^ 0x80008000u;
        pn.u[3] = pi.u[3] ^ 0x80008000u;
        const bf16x8 fr = pr.f;        // bf16(sr)
        const bf16x8 fi = pi.f;        // bf16(si)
        const bf16x8 fn = pn.f;        // -bf16(si)

        // ---- refill slot s with global kstep kab+4 (crosses tile boundary)
        if (kab + 4 < 16){
            const int nk = kab + 4;
            const float* pra = (nk < 8) ? ar0 : ar1;   // compile-time select
            const float* pia = (nk < 8) ? ai0 : ai1;
            const int kk = nk & 7;
            R0[s] = *(const float4*)(pra + kk*32 + quad*8);
            R1[s] = *(const float4*)(pra + kk*32 + quad*8 + 4);
            Q0[s] = *(const float4*)(pia + kk*32 + quad*8);
            Q1[s] = *(const float4*)(pia + kk*32 + quad*8 + 4);
        }

        // ---- MFMA cluster: swizzled LDS base for this kstep (ushort units)
        const int ub = l15*256 + ((((ks<<2) + quad) ^ xq) << 3);
        __builtin_amdgcn_s_setprio(1);
        #pragma unroll
        for (int jf = 0; jf < 8; ++jf){
            const bf16x8 br = *(const bf16x8*)&Bs[ub + jf*4096];           // Wre
            const bf16x8 bi = *(const bf16x8*)&Bs[32768 + ub + jf*4096];   // Wim
            accR[jf] = __builtin_amdgcn_mfma_f32_16x16x32_bf16(fr, br, accR[jf], 0, 0, 0);
            accR[jf] = __builtin_amdgcn_mfma_f32_16x16x32_bf16(fn, bi, accR[jf], 0, 0, 0);
            accI[jf] = __builtin_amdgcn_mfma_f32_16x16x32_bf16(fr, bi, accI[jf], 0, 0, 0);
            accI[jf] = __builtin_amdgcn_mfma_f32_16x16x32_bf16(fi, br, accI[jf], 0, 0, 0);
        }
        __builtin_amdgcn_s_setprio(0);

        // ---- tile epilogue at ks==7 (t = kab>>3, compile-time)
        if (ks == 7){
            const int t = kab >> 3;
            float sacc[4];
            #pragma unroll
            for (int r = 0; r < 4; ++r){
                float tt = 0.0f;
                #pragma unroll
                for (int jf = 0; jf < 8; ++jf){
                    const float vr = accR[jf][r];
                    const float vi = accI[jf][r];
                    tt += vr*vr + vi*vi;
                }
                tt += __shfl_xor(tt, 1);
                tt += __shfl_xor(tt, 2);
                tt += __shfl_xor(tt, 4);
                tt += __shfl_xor(tt, 8);
                sacc[r] = tt;
            }
            if (l15 == 0){
                float4 o; o.x = sacc[0]; o.y = sacc[1]; o.z = sacc[2]; o.w = sacc[3];
                *(float4*)(out + row0 + t*16 + quad*4) = o;
            }
            if (t == 0){
                #pragma unroll
                for (int jf = 0; jf < 8; ++jf){ accR[jf] = z; accI[jf] = z; }
            }
        }
    }
}

extern "C" void kernel_launch(void* const* d_in, const int* in_sizes, int n_in,
                              void* d_out, int out_size, void* d_ws, size_t ws_size,
                              hipStream_t stream){
    const float* params = (const float*)d_in[0];
    const float* sr     = (const float*)d_in[1];
    const float* si     = (const float*)d_in[2];
    unsigned short* Wimg = (unsigned short*)d_ws;   // 128 KB image
    float* out          = (float*)d_out;

    build_w_kernel<<<dim3(DIM), dim3(256), 0, stream>>>(params, Wimg);
    qform2_kernel<<<dim3(256), dim3(1024), 0, stream>>>(sr, si, Wimg, out);
}